// Round 3
// baseline (512.889 us; speedup 1.0000x reference)
//
#include <hip/hip_runtime.h>

typedef unsigned short ushort_t;

#define B_SZ 8192
#define D_SZ 1024
#define U_SZ 512
#define F_SZ 4
#define E_SZ 4
#define T_SZ 2

typedef __attribute__((ext_vector_type(8))) short bf16x8;     // 8 bf16 = 4 VGPRs (MFMA A/B frag)
typedef __attribute__((ext_vector_type(4))) float f32x4;      // MFMA C/D frag
typedef __attribute__((ext_vector_type(8))) unsigned short u16x8;

__device__ __forceinline__ unsigned short f2bf(float f) {
  union { float f; unsigned int u; } v; v.f = f;
  unsigned int r = v.u + 0x7FFFu + ((v.u >> 16) & 1u);  // RNE; inputs are finite normals
  return (unsigned short)(r >> 16);
}
__device__ __forceinline__ float bf2f(unsigned short h) {
  union { unsigned int u; float f; } v; v.u = ((unsigned int)h) << 16;
  return v.f;
}

// async global->LDS, 16B per lane; LDS dest = wave-uniform base + lane*16
__device__ __forceinline__ void gload_lds16(const void* g, void* l) {
  __builtin_amdgcn_global_load_lds(
      (const __attribute__((address_space(1))) unsigned int*)g,
      (__attribute__((address_space(3))) unsigned int*)l, 16, 0, 0);
}

// ---------------- zero the pattern counters ----------------
__global__ __launch_bounds__(64) void zero_k(int* __restrict__ cnt) {
  cnt[threadIdx.x] = 0;   // 64 counters: [field][pattern]
}

// ---------------- convert x (fp32 -> bf16) + pattern compute + row compaction ----------
// block = 256 threads * 8 elem = 2048 elem = exactly 2 rows of x.
// Threads 0 and 128 own elements 0..7 of their row -> they compute the row's patterns.
__global__ __launch_bounds__(256) void conv_x(const float* __restrict__ x,
                                              ushort_t* __restrict__ xbf,
                                              unsigned int* __restrict__ pat,
                                              int* __restrict__ rowidx,
                                              int* __restrict__ cnt) {
  const size_t i = ((size_t)blockIdx.x * 256 + threadIdx.x) * 8;
  const float4 a = *(const float4*)(x + i);
  const float4 c = *(const float4*)(x + i + 4);
  u16x8 o;
  o[0] = f2bf(a.x); o[1] = f2bf(a.y); o[2] = f2bf(a.z); o[3] = f2bf(a.w);
  o[4] = f2bf(c.x); o[5] = f2bf(c.y); o[6] = f2bf(c.z); o[7] = f2bf(c.w);
  *(u16x8*)(xbf + i) = o;

  if ((threadIdx.x & 127) == 0) {
    const int b = blockIdx.x * 2 + (threadIdx.x >> 7);
    const float* xr = x + (size_t)b * D_SZ;     // a = xr[0..3], c = xr[4..7]
    int p0 = 0, p1 = 0, p2 = 0, p3 = 0;
    p0 |= (a.x > 0.f) << 0; p0 |= (a.y > 0.f) << 1;
    p0 |= (a.z > 0.f) << 2; p0 |= (a.w > 0.f) << 3;
    p1 |= (c.x > 0.f) << 0; p1 |= (c.y > 0.f) << 1;
    p1 |= (c.z > 0.f) << 2; p1 |= (c.w > 0.f) << 3;
    const float LO[4] = {-1e10f, -0.5f, 0.f, 0.5f};
    const float HI[4] = {-0.5f, 0.f, 0.5f, 1e10f};
    const float v0 = xr[8], v1 = xr[9];
#pragma unroll
    for (int j = 0; j < 4; ++j) {
      if ((v0 > LO[j]) && (v0 <= HI[j])) p2 = 1 << j;
      if ((v1 > LO[j]) && (v1 <= HI[j])) p3 = 1 << j;
    }
    pat[b] = (unsigned int)(p0 | (p1 << 4) | (p2 << 8) | (p3 << 12));
    int pp[4] = {p0, p1, p2, p3};
#pragma unroll
    for (int f = 0; f < 4; ++f) {
      if (pp[f]) {
        const int pos = atomicAdd(&cnt[f * 16 + pp[f]], 1);
        rowidx[((size_t)f * 16 + pp[f]) * B_SZ + pos] = b;
      }
    }
  }
}

// ---------------- build tile directory (longest patterns first) ----------------
__global__ __launch_bounds__(64) void dir_k(const int* __restrict__ cnt,
                                            int* __restrict__ dir,
                                            int* __restrict__ ntiles) {
  const int f = threadIdx.x;
  if (f < 4) {
    int idx = 0;
    for (int pop = 4; pop >= 1; --pop) {
      for (int p = 1; p < 16; ++p) {
        if (__popc(p) != pop) continue;
        const int n = cnt[f * 16 + p];
        const int nt = (n + 127) >> 7;
        for (int k = 0; k < nt; ++k) dir[f * 80 + idx++] = p | (k << 8);
      }
    }
    ntiles[f] = idx;
  }
}

// ------- transpose + convert weights: 17 matrices [D][U] fp32 -> [U][D] bf16 -------
// 64x64 tiles: float4 global reads, u16x8 (16B) global writes, LDS pad 69 (2-way max).
__global__ __launch_bounds__(256) void conv_w(const float* __restrict__ Wc,
                                              const float* __restrict__ We,
                                              ushort_t* __restrict__ wbf) {
  const int blk = blockIdx.x;
  const int midx = blk >> 7;            // 128 tiles per matrix (16 d-tiles x 8 u-tiles)
  const int tid = blk & 127;
  const int trow = (tid >> 3) * 64;     // d origin
  const int tcol = (tid & 7) * 64;      // u origin
  const float* src = (midx == 0) ? Wc : (We + (size_t)(midx - 1) * D_SZ * U_SZ);
  ushort_t* dst = wbf + (size_t)midx * U_SZ * D_SZ;

  __shared__ float tile[64][69];
  const int t = threadIdx.x;
  const int r0 = t >> 2;                // 0..63 (d row within tile)
  const int cseg = (t & 3) * 16;        // 16 floats per thread along u
#pragma unroll
  for (int j = 0; j < 4; ++j) {
    const float4 v = *(const float4*)(src + (size_t)(trow + r0) * U_SZ + tcol + cseg + j * 4);
    tile[r0][cseg + j * 4 + 0] = v.x;
    tile[r0][cseg + j * 4 + 1] = v.y;
    tile[r0][cseg + j * 4 + 2] = v.z;
    tile[r0][cseg + j * 4 + 3] = v.w;
  }
  __syncthreads();
  const int u = t >> 2;                 // 0..63 (u row of output)
  const int d0 = (t & 3) * 16;          // 16 d per thread -> two 16B stores
#pragma unroll
  for (int h = 0; h < 2; ++h) {
    u16x8 ov;
#pragma unroll
    for (int k = 0; k < 8; ++k) ov[k] = f2bf(tile[d0 + h * 8 + k][u]);
    *(u16x8*)(dst + (size_t)(tcol + u) * D_SZ + trow + d0 + h * 8) = ov;
  }
}

// ---------------- gate softmax: gates[b][10] ----------------
__global__ __launch_bounds__(256) void gates_k(const float* __restrict__ x,
                                               const float* __restrict__ Wg,
                                               const float* __restrict__ bg,
                                               float* __restrict__ gates) {
  __shared__ float wgT[10 * 1024];
  const int t = threadIdx.x;
#pragma unroll
  for (int j = 0; j < 40; ++j) {
    const int i = j * 256 + t;          // coalesced read of Wg[t2][d][g]
    const int t2 = i / 5120;
    const int rem = i - t2 * 5120;
    const int d = rem / 5;
    const int g = rem - d * 5;
    wgT[(t2 * 5 + g) * 1024 + d] = Wg[i];
  }
  __syncthreads();
  const int lane = t & 63;
  const int w = t >> 6;
#pragma unroll
  for (int rr = 0; rr < 2; ++rr) {
    const int b = blockIdx.x * 8 + w * 2 + rr;
    const float* xr = x + (size_t)b * D_SZ;
    float p[10];
#pragma unroll
    for (int j = 0; j < 10; ++j) p[j] = 0.f;
#pragma unroll
    for (int i = 0; i < 4; ++i) {
      const int d0 = i * 256 + lane * 4;
      const float4 xv = *(const float4*)(xr + d0);
#pragma unroll
      for (int g = 0; g < 10; ++g) {
        const float4 wv = *(const float4*)(wgT + g * 1024 + d0);
        p[g] += xv.x * wv.x + xv.y * wv.y + xv.z * wv.z + xv.w * wv.w;
      }
    }
#pragma unroll
    for (int off = 32; off > 0; off >>= 1)
#pragma unroll
      for (int j = 0; j < 10; ++j) p[j] += __shfl_xor(p[j], off);
    float l[10];
#pragma unroll
    for (int j = 0; j < 10; ++j) l[j] = p[j] + bg[j];
    const float mx0 = fmaxf(fmaxf(fmaxf(l[0], l[1]), fmaxf(l[2], l[3])), l[4]);
    const float mx1 = fmaxf(fmaxf(fmaxf(l[5], l[6]), fmaxf(l[7], l[8])), l[9]);
    float ev[10]; float s0 = 0.f, s1 = 0.f;
#pragma unroll
    for (int g = 0; g < 5; ++g) { ev[g] = expf(l[g] - mx0); s0 += ev[g]; }
#pragma unroll
    for (int g = 5; g < 10; ++g) { ev[g] = expf(l[g] - mx1); s1 += ev[g]; }
    if (lane < 5) gates[(size_t)b * 10 + lane] = ev[lane] / s0;
    else if (lane < 10) gates[(size_t)b * 10 + lane] = ev[lane] / s1;
  }
}

// ---------------- pattern-grouped gathered bf16 MFMA GEMM ----------------
// grid = (80 tile-slots, 5 groups, 4 u-chunks). y<4: field y, tile = dir entry
// (pattern + tile-within-pattern); rows gathered via rowidx; K-passes =
// popcount(pattern), accumulate relu(acc+be) across active experts, scatter-write
// fout. y==4: common expert, direct rows, slots 0..63.
// LDS A/B tiles 128x64 bf16, 16B-chunk XOR swizzle (chunk' = chunk ^ (row&7)).
__global__ __launch_bounds__(256, 2) void gemm2(
    const ushort_t* __restrict__ xbf, const ushort_t* __restrict__ wbf,
    const int* __restrict__ rowidx, const int* __restrict__ cnt,
    const int* __restrict__ dir, const int* __restrict__ ntiles,
    const float* __restrict__ bc, const float* __restrict__ be,
    ushort_t* __restrict__ common, ushort_t* __restrict__ fout) {
  __shared__ ushort_t Ash[128 * 64];
  __shared__ ushort_t Bsh[128 * 64];
  __shared__ int ridx[128];

  const int t = threadIdx.x;
  const int lane = t & 63;
  const int w = t >> 6;          // wave 0..3, 2x2 wave grid, 64x64 per wave
  const int wm = w >> 1;
  const int wn = w & 1;
  const int quad = lane >> 4;
  const int l16 = lane & 15;
  const int f = blockIdx.y;      // 0..3 fields, 4 = common
  const int slot = blockIdx.x;
  const int u0 = blockIdx.z * 128;
  const bool isCommon = (f == 4);

  int p = 0, nrows = 128;
  if (isCommon) {
    if (slot >= 64) return;
    if (t < 128) ridx[t] = slot * 128 + t;
  } else {
    if (slot >= ntiles[f]) return;
    const int entry = dir[f * 80 + slot];
    p = entry & 15;
    const int tw = entry >> 8;
    const int n = cnt[f * 16 + p];
    const int rbase = tw * 128;
    nrows = min(128, n - rbase);
    if (t < 128) {
      const int rr = rbase + ((t < nrows) ? t : 0);   // clamp pads to first row
      ridx[t] = rowidx[((size_t)f * 16 + p) * B_SZ + rr];
    }
  }
  __syncthreads();

  // staging map: 1024 16B-chunks per tile, 4 issues/thread; XOR chunk swizzle
  size_t aoff[4]; int boff[4]; int ldsoff[4];
#pragma unroll
  for (int i = 0; i < 4; ++i) {
    const int c = (w * 4 + i) * 64 + lane;
    const int r = c >> 3;                    // tile row 0..127
    const int gc = (c & 7) ^ (r & 7);        // global chunk for this LDS slot
    aoff[i] = (size_t)ridx[r] * D_SZ + gc * 8;   // gathered A row
    boff[i] = r * D_SZ + gc * 8;                 // direct B (weight) row
    ldsoff[i] = (w * 4 + i) * 1024;              // bytes
  }

  int rowA[4], rowB[4];
#pragma unroll
  for (int i = 0; i < 4; ++i) {
    rowA[i] = wm * 64 + i * 16 + l16;
    rowB[i] = wn * 64 + i * 16 + l16;
  }
  int sw[2];
  sw[0] = ((quad) ^ (l16 & 7)) * 8;
  sw[1] = ((4 + quad) ^ (l16 & 7)) * 8;

  int elist[4]; int ne = 0;
  if (isCommon) { elist[0] = 0; ne = 1; }
  else {
#pragma unroll
    for (int e = 0; e < 4; ++e)
      if (p & (1 << e)) elist[ne++] = e;
  }

  const f32x4 fzero = {0.f, 0.f, 0.f, 0.f};
  f32x4 facc[4][4];
#pragma unroll
  for (int mi = 0; mi < 4; ++mi)
#pragma unroll
    for (int ni = 0; ni < 4; ++ni) facc[mi][ni] = fzero;

  for (int ei = 0; ei < ne; ++ei) {
    const int midx = isCommon ? 0 : (1 + f * 4 + elist[ei]);
    const ushort_t* wbase = wbf + (size_t)midx * (U_SZ * D_SZ) + (size_t)u0 * D_SZ;
    f32x4 acc[4][4];
#pragma unroll
    for (int mi = 0; mi < 4; ++mi)
#pragma unroll
      for (int ni = 0; ni < 4; ++ni) acc[mi][ni] = fzero;

    for (int k0 = 0; k0 < D_SZ; k0 += 64) {
#pragma unroll
      for (int i = 0; i < 4; ++i) {
        gload_lds16(xbf + aoff[i] + k0, (char*)Ash + ldsoff[i]);
        gload_lds16(wbase + boff[i] + k0, (char*)Bsh + ldsoff[i]);
      }
      __syncthreads();
#pragma unroll
      for (int qs = 0; qs < 2; ++qs) {
        bf16x8 av[4], bv[4];
#pragma unroll
        for (int mi = 0; mi < 4; ++mi)
          av[mi] = *(const bf16x8*)(Ash + rowA[mi] * 64 + sw[qs]);
#pragma unroll
        for (int ni = 0; ni < 4; ++ni)
          bv[ni] = *(const bf16x8*)(Bsh + rowB[ni] * 64 + sw[qs]);
#pragma unroll
        for (int mi = 0; mi < 4; ++mi)
#pragma unroll
          for (int ni = 0; ni < 4; ++ni)
            acc[mi][ni] = __builtin_amdgcn_mfma_f32_16x16x32_bf16(av[mi], bv[ni],
                                                                  acc[mi][ni], 0, 0, 0);
      }
      __syncthreads();
    }

    if (isCommon) {
#pragma unroll
      for (int mi = 0; mi < 4; ++mi) {
        const int rowb = slot * 128 + wm * 64 + mi * 16 + quad * 4;  // C/D row = quad*4+reg
#pragma unroll
        for (int ni = 0; ni < 4; ++ni) {
          const int u = u0 + wn * 64 + ni * 16 + l16;                // C/D col = lane&15
          const float bcv = bc[u];
#pragma unroll
          for (int r = 0; r < 4; ++r) {
            const float v = fmaxf(acc[mi][ni][r] + bcv, 0.f);
            common[(size_t)(rowb + r) * U_SZ + u] = f2bf(v);
          }
        }
      }
    } else {
      const float* bevp = be + (size_t)(f * 4 + elist[ei]) * U_SZ;
#pragma unroll
      for (int ni = 0; ni < 4; ++ni) {
        const int u = u0 + wn * 64 + ni * 16 + l16;
        const float bev = bevp[u];
#pragma unroll
        for (int mi = 0; mi < 4; ++mi)
#pragma unroll
          for (int r = 0; r < 4; ++r)
            facc[mi][ni][r] += fmaxf(acc[mi][ni][r] + bev, 0.f);
      }
    }
  }

  if (!isCommon) {
#pragma unroll
    for (int mi = 0; mi < 4; ++mi) {
      const int rowl = wm * 64 + mi * 16 + quad * 4;
#pragma unroll
      for (int r = 0; r < 4; ++r) {
        if (rowl + r < nrows) {
          const int brow = ridx[rowl + r];
#pragma unroll
          for (int ni = 0; ni < 4; ++ni) {
            const int u = u0 + wn * 64 + ni * 16 + l16;
            fout[((size_t)brow * F_SZ + f) * U_SZ + u] = f2bf(facc[mi][ni][r]);
          }
        }
      }
    }
  }
}

// ---------------- stage 2: att/upd scalars, blend, gate mix ----------------
__global__ __launch_bounds__(256) void stage2_k(
    const ushort_t* __restrict__ common, const ushort_t* __restrict__ fout,
    const unsigned int* __restrict__ pat, const float* __restrict__ gates,
    const float* __restrict__ Wa, const float* __restrict__ ba,
    const float* __restrict__ Wu, const float* __restrict__ bu,
    float* __restrict__ out) {
  const int b = blockIdx.x;
  const int t = threadIdx.x;
  const int lane = t & 63;
  const int w = t >> 6;
  const unsigned int pv = pat[b];

  const float c0 = bf2f(common[(size_t)b * U_SZ + t]);
  const float c1 = bf2f(common[(size_t)b * U_SZ + 256 + t]);
  float fo0[4], fo1[4];
#pragma unroll
  for (int f = 0; f < 4; ++f) {
    const bool act = ((pv >> (4 * f)) & 15u) != 0u;   // pattern 0 -> field_out is 0
    fo0[f] = act ? bf2f(fout[((size_t)b * F_SZ + f) * U_SZ + t]) : 0.f;
    fo1[f] = act ? bf2f(fout[((size_t)b * F_SZ + f) * U_SZ + 256 + t]) : 0.f;
  }
  float pa[4], pu[4];
#pragma unroll
  for (int f = 0; f < 4; ++f) {
    const float* wa = Wa + f * 1024;   // cat = [common(0..511), field(512..1023)]
    pa[f] = c0 * wa[t] + c1 * wa[256 + t] + fo0[f] * wa[512 + t] + fo1[f] * wa[768 + t];
    const float* wu = Wu + f * 1024;
    pu[f] = c0 * wu[t] + c1 * wu[256 + t] + fo0[f] * wu[512 + t] + fo1[f] * wu[768 + t];
  }
#pragma unroll
  for (int off = 32; off > 0; off >>= 1) {
#pragma unroll
    for (int f = 0; f < 4; ++f) {
      pa[f] += __shfl_xor(pa[f], off);
      pu[f] += __shfl_xor(pu[f], off);
    }
  }
  __shared__ float redA[4][4];
  __shared__ float redU[4][4];
  __shared__ float gsh[10];
  if (lane == 0) {
#pragma unroll
    for (int f = 0; f < 4; ++f) { redA[w][f] = pa[f]; redU[w][f] = pu[f]; }
  }
  if (t < 10) gsh[t] = gates[(size_t)b * 10 + t];
  __syncthreads();
  float ff0[4], ff1[4];
#pragma unroll
  for (int f = 0; f < 4; ++f) {
    const float sa = redA[0][f] + redA[1][f] + redA[2][f] + redA[3][f] + ba[f];
    const float su = redU[0][f] + redU[1][f] + redU[2][f] + redU[3][f] + bu[f];
    const float att = 1.f / (1.f + expf(-sa));
    const float upd = 1.f / (1.f + expf(-su));
    ff0[f] = upd * (att * fo0[f]) + (1.f - upd) * c0;
    ff1[f] = upd * (att * fo1[f]) + (1.f - upd) * c1;
  }
#pragma unroll
  for (int t2 = 0; t2 < 2; ++t2) {
    float v0 = gsh[t2 * 5] * c0;
    float v1 = gsh[t2 * 5] * c1;
#pragma unroll
    for (int f = 0; f < 4; ++f) {
      v0 += gsh[t2 * 5 + 1 + f] * ff0[f];
      v1 += gsh[t2 * 5 + 1 + f] * ff1[f];
    }
    out[((size_t)b * T_SZ + t2) * U_SZ + t] = v0;
    out[((size_t)b * T_SZ + t2) * U_SZ + 256 + t] = v1;
  }
}

// ---------------- launch ----------------
extern "C" void kernel_launch(void* const* d_in, const int* in_sizes, int n_in,
                              void* d_out, int out_size, void* d_ws, size_t ws_size,
                              hipStream_t stream) {
  (void)in_sizes; (void)n_in; (void)out_size; (void)ws_size;
  const float* x  = (const float*)d_in[0];
  const float* Wc = (const float*)d_in[1];
  const float* bc = (const float*)d_in[2];
  const float* We = (const float*)d_in[3];
  const float* be = (const float*)d_in[4];
  const float* Wg = (const float*)d_in[5];
  const float* bg = (const float*)d_in[6];
  const float* Wa = (const float*)d_in[7];
  const float* ba = (const float*)d_in[8];
  const float* Wu = (const float*)d_in[9];
  const float* bu = (const float*)d_in[10];
  float* out = (float*)d_out;
  char* ws = (char*)d_ws;

  // ws layout (bytes), all 16B aligned; total ~79 MB
  const size_t O_XBF    = 0;                                        // B*D*2
  const size_t O_WBF    = O_XBF + (size_t)B_SZ * D_SZ * 2;          // 17*U*D*2
  const size_t O_PAT    = O_WBF + (size_t)17 * U_SZ * D_SZ * 2;     // B*4
  const size_t O_ROWIDX = O_PAT + (size_t)B_SZ * 4;                 // 4*16*B*4
  const size_t O_CNT    = O_ROWIDX + (size_t)4 * 16 * B_SZ * 4;     // 64*4
  const size_t O_DIR    = O_CNT + 256;                              // 4*80*4
  const size_t O_NT     = O_DIR + 1280;                             // 4*4 (pad 16)
  const size_t O_GATES  = O_NT + 16;                                // B*10*4
  const size_t O_COMMON = O_GATES + (size_t)B_SZ * 10 * 4;          // B*U*2
  const size_t O_FOUT   = O_COMMON + (size_t)B_SZ * U_SZ * 2;       // B*F*U*2

  ushort_t* xbf     = (ushort_t*)(ws + O_XBF);
  ushort_t* wbf     = (ushort_t*)(ws + O_WBF);
  unsigned int* patp= (unsigned int*)(ws + O_PAT);
  int*      rowidxp = (int*)(ws + O_ROWIDX);
  int*      cntp    = (int*)(ws + O_CNT);
  int*      dirp    = (int*)(ws + O_DIR);
  int*      ntp     = (int*)(ws + O_NT);
  float*    gatesp  = (float*)(ws + O_GATES);
  ushort_t* commonp = (ushort_t*)(ws + O_COMMON);
  ushort_t* foutp   = (ushort_t*)(ws + O_FOUT);

  zero_k<<<dim3(1), dim3(64), 0, stream>>>(cntp);
  conv_x<<<dim3(4096), dim3(256), 0, stream>>>(x, xbf, patp, rowidxp, cntp);
  dir_k<<<dim3(1), dim3(64), 0, stream>>>(cntp, dirp, ntp);
  conv_w<<<dim3(17 * 128), dim3(256), 0, stream>>>(Wc, We, wbf);
  gates_k<<<dim3(1024), dim3(256), 0, stream>>>(x, Wg, bg, gatesp);
  gemm2<<<dim3(80, 5, 4), dim3(256), 0, stream>>>(xbf, wbf, rowidxp, cntp, dirp, ntp,
                                                  bc, be, commonp, foutp);
  stage2_k<<<dim3(8192), dim3(256), 0, stream>>>(commonp, foutp, patp, gatesp,
                                                 Wa, ba, Wu, bu, out);
}

// Round 4
// 331.329 us; speedup vs baseline: 1.5480x; 1.5480x over previous
//
#include <hip/hip_runtime.h>

typedef unsigned short ushort_t;

#define B_SZ 8192
#define D_SZ 1024
#define U_SZ 512
#define F_SZ 4
#define E_SZ 4
#define T_SZ 2

typedef __attribute__((ext_vector_type(8))) short bf16x8;     // 8 bf16 = 4 VGPRs (MFMA A/B frag)
typedef __attribute__((ext_vector_type(4))) float f32x4;      // MFMA C/D frag
typedef __attribute__((ext_vector_type(8))) unsigned short u16x8;

__device__ __forceinline__ unsigned short f2bf(float f) {
  union { float f; unsigned int u; } v; v.f = f;
  unsigned int r = v.u + 0x7FFFu + ((v.u >> 16) & 1u);  // RNE; inputs are finite normals
  return (unsigned short)(r >> 16);
}
__device__ __forceinline__ float bf2f(unsigned short h) {
  union { unsigned int u; float f; } v; v.u = ((unsigned int)h) << 16;
  return v.f;
}

// async global->LDS, 16B per lane; LDS dest = wave-uniform base + lane*16
__device__ __forceinline__ void gload_lds16(const void* g, void* l) {
  __builtin_amdgcn_global_load_lds(
      (const __attribute__((address_space(1))) unsigned int*)g,
      (__attribute__((address_space(3))) unsigned int*)l, 16, 0, 0);
}

// ---------------- convert x (fp32 -> bf16), pure ----------------
__global__ __launch_bounds__(256) void conv_x(const float* __restrict__ x,
                                              ushort_t* __restrict__ xbf) {
  const size_t i = ((size_t)blockIdx.x * 256 + threadIdx.x) * 8;
  const float4 a = *(const float4*)(x + i);
  const float4 c = *(const float4*)(x + i + 4);
  u16x8 o;
  o[0] = f2bf(a.x); o[1] = f2bf(a.y); o[2] = f2bf(a.z); o[3] = f2bf(a.w);
  o[4] = f2bf(c.x); o[5] = f2bf(c.y); o[6] = f2bf(c.z); o[7] = f2bf(c.w);
  *(u16x8*)(xbf + i) = o;
}

// ---------------- phase 1: patterns + per-block LDS histogram ----------------
// One thread per row; LDS atomics only (per-CU, no cross-XCD serialization).
__global__ __launch_bounds__(128) void pat_k(const float* __restrict__ x,
                                             unsigned int* __restrict__ pat,
                                             unsigned int* __restrict__ rowinfo,
                                             int* __restrict__ blockhist) {
  __shared__ int hist[64];
  const int t = threadIdx.x;
  if (t < 64) hist[t] = 0;
  __syncthreads();
  const int b = blockIdx.x * 128 + t;
  const float4 a = *(const float4*)(x + (size_t)b * D_SZ);
  const float4 c = *(const float4*)(x + (size_t)b * D_SZ + 4);
  const float v0 = x[(size_t)b * D_SZ + 8];
  const float v1 = x[(size_t)b * D_SZ + 9];
  int pp[4];
  pp[0] = (int)(a.x > 0.f) | ((int)(a.y > 0.f) << 1) |
          ((int)(a.z > 0.f) << 2) | ((int)(a.w > 0.f) << 3);
  pp[1] = (int)(c.x > 0.f) | ((int)(c.y > 0.f) << 1) |
          ((int)(c.z > 0.f) << 2) | ((int)(c.w > 0.f) << 3);
  const float LO[4] = {-1e10f, -0.5f, 0.f, 0.5f};
  const float HI[4] = {-0.5f, 0.f, 0.5f, 1e10f};
  pp[2] = 0; pp[3] = 0;
#pragma unroll
  for (int j = 0; j < 4; ++j) {
    if ((v0 > LO[j]) && (v0 <= HI[j])) pp[2] = 1 << j;
    if ((v1 > LO[j]) && (v1 <= HI[j])) pp[3] = 1 << j;
  }
  pat[b] = (unsigned int)(pp[0] | (pp[1] << 4) | (pp[2] << 8) | (pp[3] << 12));
  unsigned int info = 0;
#pragma unroll
  for (int f = 0; f < 4; ++f) {
    if (pp[f]) {
      const int lp = atomicAdd(&hist[f * 16 + pp[f]], 1);   // LDS atomic
      info |= (unsigned int)lp << (8 * f);
    }
  }
  rowinfo[b] = info;
  __syncthreads();
  if (t < 64) blockhist[blockIdx.x * 64 + t] = hist[t];
}

// ---------------- phase 2: scan block histograms + build directory ----------------
__global__ __launch_bounds__(64) void scan_k(const int* __restrict__ blockhist,
                                             int* __restrict__ base,
                                             int* __restrict__ cnt,
                                             int* __restrict__ dir,
                                             int* __restrict__ ntiles) {
  const int fp = threadIdx.x;  // 0..63 = [field][pattern]
  int run = 0;
  for (int blk = 0; blk < 64; ++blk) {
    base[blk * 64 + fp] = run;
    run += blockhist[blk * 64 + fp];
  }
  cnt[fp] = run;
  __syncthreads();
  if (fp < 4) {
    const int f = fp;
    int idx = 0;
    for (int pop = 4; pop >= 1; --pop) {
      for (int p = 1; p < 16; ++p) {
        if (__popc(p) != pop) continue;
        const int n = cnt[f * 16 + p];
        const int nt = (n + 127) >> 7;
        for (int k = 0; k < nt; ++k) dir[f * 80 + idx++] = p | (k << 8);
      }
    }
    ntiles[f] = idx;
  }
}

// ---------------- phase 3: scatter row indices (no atomics) ----------------
__global__ __launch_bounds__(128) void scat_k(const unsigned int* __restrict__ pat,
                                              const unsigned int* __restrict__ rowinfo,
                                              const int* __restrict__ base,
                                              int* __restrict__ rowidx) {
  const int t = threadIdx.x;
  const int b = blockIdx.x * 128 + t;
  const unsigned int pv = pat[b];
  const unsigned int info = rowinfo[b];
#pragma unroll
  for (int f = 0; f < 4; ++f) {
    const int p = (int)((pv >> (4 * f)) & 15u);
    if (p) {
      const int pos = base[blockIdx.x * 64 + f * 16 + p] + (int)((info >> (8 * f)) & 255u);
      rowidx[((size_t)(f * 16 + p)) * B_SZ + pos] = b;
    }
  }
}

// ------- transpose + convert weights: 17 matrices [D][U] fp32 -> [U][D] bf16 -------
// 64x64 tiles: float4 global reads, u16x8 (16B) global writes, LDS pad 69 (2-way max).
__global__ __launch_bounds__(256) void conv_w(const float* __restrict__ Wc,
                                              const float* __restrict__ We,
                                              ushort_t* __restrict__ wbf) {
  const int blk = blockIdx.x;
  const int midx = blk >> 7;            // 128 tiles per matrix (16 d-tiles x 8 u-tiles)
  const int tid = blk & 127;
  const int trow = (tid >> 3) * 64;     // d origin
  const int tcol = (tid & 7) * 64;      // u origin
  const float* src = (midx == 0) ? Wc : (We + (size_t)(midx - 1) * D_SZ * U_SZ);
  ushort_t* dst = wbf + (size_t)midx * U_SZ * D_SZ;

  __shared__ float tile[64][69];
  const int t = threadIdx.x;
  const int r0 = t >> 2;                // 0..63 (d row within tile)
  const int cseg = (t & 3) * 16;        // 16 floats per thread along u
#pragma unroll
  for (int j = 0; j < 4; ++j) {
    const float4 v = *(const float4*)(src + (size_t)(trow + r0) * U_SZ + tcol + cseg + j * 4);
    tile[r0][cseg + j * 4 + 0] = v.x;
    tile[r0][cseg + j * 4 + 1] = v.y;
    tile[r0][cseg + j * 4 + 2] = v.z;
    tile[r0][cseg + j * 4 + 3] = v.w;
  }
  __syncthreads();
  const int u = t >> 2;                 // 0..63 (u row of output)
  const int d0 = (t & 3) * 16;          // 16 d per thread -> two 16B stores
#pragma unroll
  for (int h = 0; h < 2; ++h) {
    u16x8 ov;
#pragma unroll
    for (int k = 0; k < 8; ++k) ov[k] = f2bf(tile[d0 + h * 8 + k][u]);
    *(u16x8*)(dst + (size_t)(tcol + u) * D_SZ + trow + d0 + h * 8) = ov;
  }
}

// ---------------- gate softmax: gates[b][10] ----------------
__global__ __launch_bounds__(256) void gates_k(const float* __restrict__ x,
                                               const float* __restrict__ Wg,
                                               const float* __restrict__ bg,
                                               float* __restrict__ gates) {
  __shared__ float wgT[10 * 1024];
  const int t = threadIdx.x;
#pragma unroll
  for (int j = 0; j < 40; ++j) {
    const int i = j * 256 + t;          // coalesced read of Wg[t2][d][g]
    const int t2 = i / 5120;
    const int rem = i - t2 * 5120;
    const int d = rem / 5;
    const int g = rem - d * 5;
    wgT[(t2 * 5 + g) * 1024 + d] = Wg[i];
  }
  __syncthreads();
  const int lane = t & 63;
  const int w = t >> 6;
#pragma unroll
  for (int rr = 0; rr < 2; ++rr) {
    const int b = blockIdx.x * 8 + w * 2 + rr;
    const float* xr = x + (size_t)b * D_SZ;
    float p[10];
#pragma unroll
    for (int j = 0; j < 10; ++j) p[j] = 0.f;
#pragma unroll
    for (int i = 0; i < 4; ++i) {
      const int d0 = i * 256 + lane * 4;
      const float4 xv = *(const float4*)(xr + d0);
#pragma unroll
      for (int g = 0; g < 10; ++g) {
        const float4 wv = *(const float4*)(wgT + g * 1024 + d0);
        p[g] += xv.x * wv.x + xv.y * wv.y + xv.z * wv.z + xv.w * wv.w;
      }
    }
#pragma unroll
    for (int off = 32; off > 0; off >>= 1)
#pragma unroll
      for (int j = 0; j < 10; ++j) p[j] += __shfl_xor(p[j], off);
    float l[10];
#pragma unroll
    for (int j = 0; j < 10; ++j) l[j] = p[j] + bg[j];
    const float mx0 = fmaxf(fmaxf(fmaxf(l[0], l[1]), fmaxf(l[2], l[3])), l[4]);
    const float mx1 = fmaxf(fmaxf(fmaxf(l[5], l[6]), fmaxf(l[7], l[8])), l[9]);
    float ev[10]; float s0 = 0.f, s1 = 0.f;
#pragma unroll
    for (int g = 0; g < 5; ++g) { ev[g] = expf(l[g] - mx0); s0 += ev[g]; }
#pragma unroll
    for (int g = 5; g < 10; ++g) { ev[g] = expf(l[g] - mx1); s1 += ev[g]; }
    if (lane < 5) gates[(size_t)b * 10 + lane] = ev[lane] / s0;
    else if (lane < 10) gates[(size_t)b * 10 + lane] = ev[lane] / s1;
  }
}

// ---------------- pattern-grouped gathered bf16 MFMA GEMM ----------------
// grid = (80 tile-slots, 5 groups, 4 u-chunks). y<4: field y, tile = dir entry
// (pattern + tile-within-pattern); rows gathered via rowidx; K-passes =
// popcount(pattern), accumulate relu(acc+be) across active experts, scatter-write
// fout. y==4: common expert, direct rows, slots 0..63.
// LDS A/B tiles 128x64 bf16, 16B-chunk XOR swizzle (chunk' = chunk ^ (row&7)).
__global__ __launch_bounds__(256, 2) void gemm2(
    const ushort_t* __restrict__ xbf, const ushort_t* __restrict__ wbf,
    const int* __restrict__ rowidx, const int* __restrict__ cnt,
    const int* __restrict__ dir, const int* __restrict__ ntiles,
    const float* __restrict__ bc, const float* __restrict__ be,
    ushort_t* __restrict__ common, ushort_t* __restrict__ fout) {
  __shared__ ushort_t Ash[128 * 64];
  __shared__ ushort_t Bsh[128 * 64];
  __shared__ int ridx[128];

  const int t = threadIdx.x;
  const int lane = t & 63;
  const int w = t >> 6;          // wave 0..3, 2x2 wave grid, 64x64 per wave
  const int wm = w >> 1;
  const int wn = w & 1;
  const int quad = lane >> 4;
  const int l16 = lane & 15;
  const int f = blockIdx.y;      // 0..3 fields, 4 = common
  const int slot = blockIdx.x;
  const int u0 = blockIdx.z * 128;
  const bool isCommon = (f == 4);

  int p = 0, nrows = 128;
  if (isCommon) {
    if (slot >= 64) return;
    if (t < 128) ridx[t] = slot * 128 + t;
  } else {
    if (slot >= ntiles[f]) return;
    const int entry = dir[f * 80 + slot];
    p = entry & 15;
    const int tw = entry >> 8;
    const int n = cnt[f * 16 + p];
    const int rbase = tw * 128;
    nrows = min(128, n - rbase);
    if (t < 128) {
      const int rr = rbase + ((t < nrows) ? t : 0);   // clamp pads to first row
      ridx[t] = rowidx[((size_t)f * 16 + p) * B_SZ + rr];
    }
  }
  __syncthreads();

  // staging map: 1024 16B-chunks per tile, 4 issues/thread; XOR chunk swizzle
  size_t aoff[4]; int boff[4]; int ldsoff[4];
#pragma unroll
  for (int i = 0; i < 4; ++i) {
    const int c = (w * 4 + i) * 64 + lane;
    const int r = c >> 3;                    // tile row 0..127
    const int gc = (c & 7) ^ (r & 7);        // global chunk for this LDS slot
    aoff[i] = (size_t)ridx[r] * D_SZ + gc * 8;   // gathered A row
    boff[i] = r * D_SZ + gc * 8;                 // direct B (weight) row
    ldsoff[i] = (w * 4 + i) * 1024;              // bytes
  }

  int rowA[4], rowB[4];
#pragma unroll
  for (int i = 0; i < 4; ++i) {
    rowA[i] = wm * 64 + i * 16 + l16;
    rowB[i] = wn * 64 + i * 16 + l16;
  }
  int sw[2];
  sw[0] = ((quad) ^ (l16 & 7)) * 8;
  sw[1] = ((4 + quad) ^ (l16 & 7)) * 8;

  int elist[4]; int ne = 0;
  if (isCommon) { elist[0] = 0; ne = 1; }
  else {
#pragma unroll
    for (int e = 0; e < 4; ++e)
      if (p & (1 << e)) elist[ne++] = e;
  }

  const f32x4 fzero = {0.f, 0.f, 0.f, 0.f};
  f32x4 facc[4][4];
#pragma unroll
  for (int mi = 0; mi < 4; ++mi)
#pragma unroll
    for (int ni = 0; ni < 4; ++ni) facc[mi][ni] = fzero;

  for (int ei = 0; ei < ne; ++ei) {
    const int midx = isCommon ? 0 : (1 + f * 4 + elist[ei]);
    const ushort_t* wbase = wbf + (size_t)midx * (U_SZ * D_SZ) + (size_t)u0 * D_SZ;
    f32x4 acc[4][4];
#pragma unroll
    for (int mi = 0; mi < 4; ++mi)
#pragma unroll
      for (int ni = 0; ni < 4; ++ni) acc[mi][ni] = fzero;

    for (int k0 = 0; k0 < D_SZ; k0 += 64) {
#pragma unroll
      for (int i = 0; i < 4; ++i) {
        gload_lds16(xbf + aoff[i] + k0, (char*)Ash + ldsoff[i]);
        gload_lds16(wbase + boff[i] + k0, (char*)Bsh + ldsoff[i]);
      }
      __syncthreads();
#pragma unroll
      for (int qs = 0; qs < 2; ++qs) {
        bf16x8 av[4], bv[4];
#pragma unroll
        for (int mi = 0; mi < 4; ++mi)
          av[mi] = *(const bf16x8*)(Ash + rowA[mi] * 64 + sw[qs]);
#pragma unroll
        for (int ni = 0; ni < 4; ++ni)
          bv[ni] = *(const bf16x8*)(Bsh + rowB[ni] * 64 + sw[qs]);
#pragma unroll
        for (int mi = 0; mi < 4; ++mi)
#pragma unroll
          for (int ni = 0; ni < 4; ++ni)
            acc[mi][ni] = __builtin_amdgcn_mfma_f32_16x16x32_bf16(av[mi], bv[ni],
                                                                  acc[mi][ni], 0, 0, 0);
      }
      __syncthreads();
    }

    if (isCommon) {
#pragma unroll
      for (int mi = 0; mi < 4; ++mi) {
        const int rowb = slot * 128 + wm * 64 + mi * 16 + quad * 4;  // C/D row = quad*4+reg
#pragma unroll
        for (int ni = 0; ni < 4; ++ni) {
          const int u = u0 + wn * 64 + ni * 16 + l16;                // C/D col = lane&15
          const float bcv = bc[u];
#pragma unroll
          for (int r = 0; r < 4; ++r) {
            const float v = fmaxf(acc[mi][ni][r] + bcv, 0.f);
            common[(size_t)(rowb + r) * U_SZ + u] = f2bf(v);
          }
        }
      }
    } else {
      const float* bevp = be + (size_t)(f * 4 + elist[ei]) * U_SZ;
#pragma unroll
      for (int ni = 0; ni < 4; ++ni) {
        const int u = u0 + wn * 64 + ni * 16 + l16;
        const float bev = bevp[u];
#pragma unroll
        for (int mi = 0; mi < 4; ++mi)
#pragma unroll
          for (int r = 0; r < 4; ++r)
            facc[mi][ni][r] += fmaxf(acc[mi][ni][r] + bev, 0.f);
      }
    }
  }

  if (!isCommon) {
#pragma unroll
    for (int mi = 0; mi < 4; ++mi) {
      const int rowl = wm * 64 + mi * 16 + quad * 4;
#pragma unroll
      for (int r = 0; r < 4; ++r) {
        if (rowl + r < nrows) {
          const int brow = ridx[rowl + r];
#pragma unroll
          for (int ni = 0; ni < 4; ++ni) {
            const int u = u0 + wn * 64 + ni * 16 + l16;
            fout[((size_t)brow * F_SZ + f) * U_SZ + u] = f2bf(facc[mi][ni][r]);
          }
        }
      }
    }
  }
}

// ---------------- stage 2: att/upd scalars, blend, gate mix ----------------
__global__ __launch_bounds__(256) void stage2_k(
    const ushort_t* __restrict__ common, const ushort_t* __restrict__ fout,
    const unsigned int* __restrict__ pat, const float* __restrict__ gates,
    const float* __restrict__ Wa, const float* __restrict__ ba,
    const float* __restrict__ Wu, const float* __restrict__ bu,
    float* __restrict__ out) {
  const int b = blockIdx.x;
  const int t = threadIdx.x;
  const int lane = t & 63;
  const int w = t >> 6;
  const unsigned int pv = pat[b];

  const float c0 = bf2f(common[(size_t)b * U_SZ + t]);
  const float c1 = bf2f(common[(size_t)b * U_SZ + 256 + t]);
  float fo0[4], fo1[4];
#pragma unroll
  for (int f = 0; f < 4; ++f) {
    const bool act = ((pv >> (4 * f)) & 15u) != 0u;   // pattern 0 -> field_out is 0
    fo0[f] = act ? bf2f(fout[((size_t)b * F_SZ + f) * U_SZ + t]) : 0.f;
    fo1[f] = act ? bf2f(fout[((size_t)b * F_SZ + f) * U_SZ + 256 + t]) : 0.f;
  }
  float pa[4], pu[4];
#pragma unroll
  for (int f = 0; f < 4; ++f) {
    const float* wa = Wa + f * 1024;   // cat = [common(0..511), field(512..1023)]
    pa[f] = c0 * wa[t] + c1 * wa[256 + t] + fo0[f] * wa[512 + t] + fo1[f] * wa[768 + t];
    const float* wu = Wu + f * 1024;
    pu[f] = c0 * wu[t] + c1 * wu[256 + t] + fo0[f] * wu[512 + t] + fo1[f] * wu[768 + t];
  }
#pragma unroll
  for (int off = 32; off > 0; off >>= 1) {
#pragma unroll
    for (int f = 0; f < 4; ++f) {
      pa[f] += __shfl_xor(pa[f], off);
      pu[f] += __shfl_xor(pu[f], off);
    }
  }
  __shared__ float redA[4][4];
  __shared__ float redU[4][4];
  __shared__ float gsh[10];
  if (lane == 0) {
#pragma unroll
    for (int f = 0; f < 4; ++f) { redA[w][f] = pa[f]; redU[w][f] = pu[f]; }
  }
  if (t < 10) gsh[t] = gates[(size_t)b * 10 + t];
  __syncthreads();
  float ff0[4], ff1[4];
#pragma unroll
  for (int f = 0; f < 4; ++f) {
    const float sa = redA[0][f] + redA[1][f] + redA[2][f] + redA[3][f] + ba[f];
    const float su = redU[0][f] + redU[1][f] + redU[2][f] + redU[3][f] + bu[f];
    const float att = 1.f / (1.f + expf(-sa));
    const float upd = 1.f / (1.f + expf(-su));
    ff0[f] = upd * (att * fo0[f]) + (1.f - upd) * c0;
    ff1[f] = upd * (att * fo1[f]) + (1.f - upd) * c1;
  }
#pragma unroll
  for (int t2 = 0; t2 < 2; ++t2) {
    float v0 = gsh[t2 * 5] * c0;
    float v1 = gsh[t2 * 5] * c1;
#pragma unroll
    for (int f = 0; f < 4; ++f) {
      v0 += gsh[t2 * 5 + 1 + f] * ff0[f];
      v1 += gsh[t2 * 5 + 1 + f] * ff1[f];
    }
    out[((size_t)b * T_SZ + t2) * U_SZ + t] = v0;
    out[((size_t)b * T_SZ + t2) * U_SZ + 256 + t] = v1;
  }
}

// ---------------- launch ----------------
extern "C" void kernel_launch(void* const* d_in, const int* in_sizes, int n_in,
                              void* d_out, int out_size, void* d_ws, size_t ws_size,
                              hipStream_t stream) {
  (void)in_sizes; (void)n_in; (void)out_size; (void)ws_size;
  const float* x  = (const float*)d_in[0];
  const float* Wc = (const float*)d_in[1];
  const float* bc = (const float*)d_in[2];
  const float* We = (const float*)d_in[3];
  const float* be = (const float*)d_in[4];
  const float* Wg = (const float*)d_in[5];
  const float* bg = (const float*)d_in[6];
  const float* Wa = (const float*)d_in[7];
  const float* ba = (const float*)d_in[8];
  const float* Wu = (const float*)d_in[9];
  const float* bu = (const float*)d_in[10];
  float* out = (float*)d_out;
  char* ws = (char*)d_ws;

  // ws layout (bytes), all 16B aligned; total ~79.1 MB
  const size_t O_XBF    = 0;                                        // B*D*2
  const size_t O_WBF    = O_XBF + (size_t)B_SZ * D_SZ * 2;          // 17*U*D*2
  const size_t O_PAT    = O_WBF + (size_t)17 * U_SZ * D_SZ * 2;     // B*4
  const size_t O_ROWIDX = O_PAT + (size_t)B_SZ * 4;                 // 4*16*B*4
  const size_t O_CNT    = O_ROWIDX + (size_t)4 * 16 * B_SZ * 4;     // 64*4
  const size_t O_DIR    = O_CNT + 256;                              // 4*80*4
  const size_t O_NT     = O_DIR + 1280;                             // 4*4 (pad 16)
  const size_t O_GATES  = O_NT + 16;                                // B*10*4
  const size_t O_COMMON = O_GATES + (size_t)B_SZ * 10 * 4;          // B*U*2
  const size_t O_FOUT   = O_COMMON + (size_t)B_SZ * U_SZ * 2;       // B*F*U*2
  const size_t O_RINFO  = O_FOUT + (size_t)B_SZ * F_SZ * U_SZ * 2;  // B*4
  const size_t O_BHIST  = O_RINFO + (size_t)B_SZ * 4;               // 64*64*4
  const size_t O_BASE   = O_BHIST + 64 * 64 * 4;                    // 64*64*4

  ushort_t* xbf     = (ushort_t*)(ws + O_XBF);
  ushort_t* wbf     = (ushort_t*)(ws + O_WBF);
  unsigned int* patp= (unsigned int*)(ws + O_PAT);
  int*      rowidxp = (int*)(ws + O_ROWIDX);
  int*      cntp    = (int*)(ws + O_CNT);
  int*      dirp    = (int*)(ws + O_DIR);
  int*      ntp     = (int*)(ws + O_NT);
  float*    gatesp  = (float*)(ws + O_GATES);
  ushort_t* commonp = (ushort_t*)(ws + O_COMMON);
  ushort_t* foutp   = (ushort_t*)(ws + O_FOUT);
  unsigned int* rinfop = (unsigned int*)(ws + O_RINFO);
  int*      bhistp  = (int*)(ws + O_BHIST);
  int*      basep   = (int*)(ws + O_BASE);

  conv_x<<<dim3(4096), dim3(256), 0, stream>>>(x, xbf);
  pat_k<<<dim3(64), dim3(128), 0, stream>>>(x, patp, rinfop, bhistp);
  scan_k<<<dim3(1), dim3(64), 0, stream>>>(bhistp, basep, cntp, dirp, ntp);
  scat_k<<<dim3(64), dim3(128), 0, stream>>>(patp, rinfop, basep, rowidxp);
  conv_w<<<dim3(17 * 128), dim3(256), 0, stream>>>(Wc, We, wbf);
  gates_k<<<dim3(1024), dim3(256), 0, stream>>>(x, Wg, bg, gatesp);
  gemm2<<<dim3(80, 5, 4), dim3(256), 0, stream>>>(xbf, wbf, rowidxp, cntp, dirp, ntp,
                                                  bc, be, commonp, foutp);
  stage2_k<<<dim3(8192), dim3(256), 0, stream>>>(commonp, foutp, patp, gatesp,
                                                 Wa, ba, Wu, bu, out);
}